// Round 4
// baseline (11173.138 us; speedup 1.0000x reference)
//
#include <hip/hip_runtime.h>

#define T_TOTAL 2048

typedef short bf16x8 __attribute__((ext_vector_type(8)));
typedef float f32x4 __attribute__((ext_vector_type(4)));

// workspace layout (bytes)
#define OFF_WT  0ull                      // W_t bf16 [2][1024 col][256 k]      (1 MiB)
#define OFF_UT  (1ull<<20)                // U slots bf16 [2][512 slot][64][16B](1 MiB)
#define OFF_HST (2ull<<20)                // h state f32 [2][64][256]
#define OFF_CST (OFF_HST + (128ull<<10))  // c state f32 [2][64][256]
#define OFF_XW  (3ull<<20)                // xw ring bf16 [Tseg][2][4][1024][16]
#define STEP_BYTES 262144ull              // one step of xw (bf16)

__device__ __forceinline__ unsigned short f2bf(float f){
  unsigned int u = __builtin_bit_cast(unsigned int, f);
  u += 0x7fffu + ((u>>16)&1u);
  return (unsigned short)(u>>16);
}
__device__ __forceinline__ float bfhi2f(unsigned int u){
  unsigned int v = u & 0xffff0000u; return __builtin_bit_cast(float, v);
}
__device__ __forceinline__ float bflo2f(unsigned int u){
  unsigned int v = u << 16; return __builtin_bit_cast(float, v);
}
__device__ __forceinline__ float sigf(float z){ return 1.0f/(1.0f + __expf(-z)); }
__device__ __forceinline__ float tanhf_(float z){ return 2.0f/(1.0f + __expf(-2.0f*z)) - 1.0f; }

// ---------------- prep: W -> [dir][col][k] bf16 ; U -> fragment slots ------
__global__ __launch_bounds__(256) void kprep(const float* __restrict__ Wf, const float* __restrict__ Uf,
                                             const float* __restrict__ Wb, const float* __restrict__ Ub,
                                             unsigned short* __restrict__ ws){
  __shared__ float tile[64][65];
  int mat = blockIdx.z; // 0 Wf, 1 Wb, 2 Uf, 3 Ub
  const float* src = (mat==0)?Wf:(mat==1)?Wb:(mat==2)?Uf:Ub;
  int c0 = blockIdx.x*64, k0 = blockIdx.y*64;
  int tx = threadIdx.x & 63, ty = threadIdx.x >> 6;
  #pragma unroll
  for (int j=0;j<16;j++){
    int r = j*4+ty;
    tile[r][tx] = src[(size_t)(k0+r)*1024 + (c0+tx)];
  }
  __syncthreads();
  if (mat < 2){
    unsigned short* dst = ws + (unsigned)mat*262144u;
    #pragma unroll
    for (int j=0;j<16;j++){
      int r = j*4+ty;
      dst[(size_t)(c0+r)*256 + (k0+tx)] = f2bf(tile[tx][r]);
    }
  } else {
    unsigned short* dst = ws + 524288u + (unsigned)(mat&1)*262144u;
    #pragma unroll
    for (int j=0;j<16;j++){
      int r = j*4+ty;
      int col = c0+r, k = k0+tx;
      int cg = col>>4, ks = k>>5, kq = (k>>3)&3, e = k&7;
      dst[(size_t)(cg*8+ks)*512 + ((col&15)+16*kq)*8 + e] = f2bf(tile[tx][r]);
    }
  }
}

// ---------------- xw GEMM (two passes of 16 col-tiles; fits 128 VGPR) ------
__global__ __launch_bounds__(512) void kgemm(const float* __restrict__ x,
        const float* __restrict__ biasF, const float* __restrict__ biasB,
        const unsigned short* __restrict__ wsu, char* __restrict__ xw, int s0){
  __shared__ __align__(16) char axs[32768]; // A slots: [q][ks][L][16B]
  int dir = blockIdx.y;
  int sg = s0 + blockIdx.x;
  int t_src = dir ? (T_TOTAL-1-sg) : sg;
  int tid = threadIdx.x, w = tid>>6, l = tid&63;
  int l15 = l&15, kq = l>>4;
  {
    int ks = l>>3, kqx = (l>>1)&3, e0 = (l&1)*4;
    #pragma unroll
    for (int i=0;i<8;i++){
      int b = w + 8*i;
      const float* px = x + ((size_t)b*T_TOTAL + t_src)*256 + 4*l;
      float4 v = *(const float4*)px;
      uint2 pk;
      pk.x = (unsigned)f2bf(v.x) | ((unsigned)f2bf(v.y)<<16);
      pk.y = (unsigned)f2bf(v.z) | ((unsigned)f2bf(v.w)<<16);
      *(uint2*)(axs + ((b>>4)*8192 + ks*1024 + ((b&15) + 16*kqx)*16 + e0*2)) = pk;
    }
  }
  __syncthreads();
  int q = w>>1, ch = w&1;
  const unsigned short* WT = wsu + (size_t)dir*262144u;
  const float* bias = dir ? biasB : biasF;
  char* outp = xw + (size_t)blockIdx.x*STEP_BYTES + (size_t)dir*131072u + (size_t)q*32768u;
  #pragma unroll
  for (int half=0; half<2; ++half){
    f32x4 acc[16];
    #pragma unroll
    for (int ct2=0;ct2<16;ct2++){
      float bv = bias[ch*512 + (half*16+ct2)*16 + l15];
      acc[ct2][0]=bv; acc[ct2][1]=bv; acc[ct2][2]=bv; acc[ct2][3]=bv;
    }
    #pragma unroll
    for (int ks=0;ks<8;ks++){
      bf16x8 a = *(const bf16x8*)(axs + q*8192 + ks*1024 + l*16);
      #pragma unroll
      for (int ct2=0;ct2<16;ct2++){
        int col = ch*512 + (half*16+ct2)*16 + l15;
        const char* bp = (const char*)WT + (size_t)col*512 + ks*64 + kq*16;
        bf16x8 b = *(const bf16x8*)bp;
        acc[ct2] = __builtin_amdgcn_mfma_f32_16x16x32_bf16(a, b, acc[ct2], 0, 0, 0);
      }
    }
    #pragma unroll
    for (int ct2=0;ct2<16;ct2++){
      int col = ch*512 + (half*16+ct2)*16 + l15;
      uint2 pk;
      pk.x = (unsigned)f2bf(acc[ct2][0]) | ((unsigned)f2bf(acc[ct2][1])<<16);
      pk.y = (unsigned)f2bf(acc[ct2][2]) | ((unsigned)f2bf(acc[ct2][3])<<16);
      *(uint2*)(outp + (size_t)col*32 + kq*8) = pk;
    }
  }
}

// ---------------- recurrent scan: 8 blocks = 2 dirs x 4 batch-quads --------
// U fully on-chip: ks0..5 in regs (192 VGPR), ks6..7 in LDS (128 KiB).
// STATIC 136 KiB LDS => compile-time occupancy = 2 waves/EU => 256-VGPR budget.
__global__ __launch_bounds__(512) __attribute__((amdgpu_waves_per_eu(2, 2)))
void krec(const unsigned short* __restrict__ wsu,
        const char* __restrict__ xw, float* __restrict__ hst, float* __restrict__ cst,
        float* __restrict__ out, int nsteps, int first, int last){
  __shared__ __align__(16) char smem[139264];
  char* hsl = smem + 131072; // h slots: ks*1024 + L*16 (8 KiB)
  int bid = blockIdx.x;
  int dir = bid>>2, q = bid&3;
  int tid = threadIdx.x, w = tid>>6, l = tid&63;
  int l15 = l&15, kq = l>>4;
  const char* UT = (const char*)(wsu + 524288u + (size_t)dir*262144u);

  bf16x8 ur[2][4][6];
  #pragma unroll
  for (int s=0;s<2;s++){
    #pragma unroll
    for (int g=0;g<4;g++){
      int cg = g*16 + 2*w + s;
      const char* base = UT + (size_t)cg*8192 + (size_t)l*16;
      #pragma unroll
      for (int ks=0;ks<6;ks++) ur[s][g][ks] = *(const bf16x8*)(base + ks*1024);
      #pragma unroll
      for (int k2=0;k2<2;k2++){
        bf16x8 t = *(const bf16x8*)(base + (6+k2)*1024);
        *(bf16x8*)(smem + ((((w*2+s)*4+g)*2+k2)*1024 + l*16)) = t;
      }
    }
  }

  float c_[2][4];
  if (first){
    #pragma unroll
    for (int s=0;s<2;s++){
      #pragma unroll
      for (int r=0;r<4;r++) c_[s][r]=0.0f;
    }
    *(uint4*)(hsl + tid*16) = make_uint4(0u,0u,0u,0u);
  } else {
    #pragma unroll
    for (int s=0;s<2;s++){
      #pragma unroll
      for (int r=0;r<4;r++){
        int b = 4*kq + r, j = 32*w + 16*s + l15;
        size_t off = ((size_t)dir*64 + q*16 + b)*256 + j;
        float hv = hst[off];
        c_[s][r] = cst[off];
        int L = b + 16*((j>>3)&3);
        *(unsigned short*)(hsl + (j>>5)*1024 + L*16 + (j&7)*2) = f2bf(hv);
      }
    }
  }
  __syncthreads();

  const char* XW = xw + (size_t)dir*131072u + (size_t)q*32768u;
  uint2 xpf[2][4];
  #pragma unroll
  for (int s=0;s<2;s++){
    #pragma unroll
    for (int g=0;g<4;g++){
      int col = g*256 + 32*w + 16*s + l15;
      xpf[s][g] = *(const uint2*)(XW + (size_t)col*32 + kq*8);
    }
  }

  float hval[2][4];
  for (int t=0; t<nsteps; ++t){
    #pragma unroll
    for (int s=0;s<2;s++){
      f32x4 acc[4];
      #pragma unroll
      for (int g=0;g<4;g++){
        uint2 v = xpf[s][g];
        acc[g][0]=bflo2f(v.x); acc[g][1]=bfhi2f(v.x);
        acc[g][2]=bflo2f(v.y); acc[g][3]=bfhi2f(v.y);
      }
      { // prefetch next step's xw half (consumed only next iteration)
        int tn = (t+1 < nsteps) ? (t+1) : t;
        #pragma unroll
        for (int g=0;g<4;g++){
          int col = g*256 + 32*w + 16*s + l15;
          xpf[s][g] = *(const uint2*)(XW + (size_t)tn*STEP_BYTES + (size_t)col*32 + kq*8);
        }
      }
      #pragma unroll
      for (int ks=0;ks<8;ks++){
        bf16x8 a = *(const bf16x8*)(hsl + ks*1024 + l*16);
        #pragma unroll
        for (int g=0;g<4;g++){
          bf16x8 b;
          if (ks<6) b = ur[s][g][ks];
          else      b = *(const bf16x8*)(smem + ((((w*2+s)*4+g)*2+(ks-6))*1024 + l*16));
          acc[g] = __builtin_amdgcn_mfma_f32_16x16x32_bf16(a, b, acc[g], 0, 0, 0);
        }
      }
      #pragma unroll
      for (int r=0;r<4;r++){
        float ig = sigf(acc[0][r]);
        float fg = sigf(acc[1][r]);
        float gg = tanhf_(acc[2][r]);
        float og = sigf(acc[3][r]);
        float cn = fg*c_[s][r] + ig*gg;
        c_[s][r] = cn;
        hval[s][r] = og*tanhf_(cn);
      }
    }
    __syncthreads();   // all waves done reading h(t)
    if (t == nsteps-1){
      if (last){
        #pragma unroll
        for (int s=0;s<2;s++){
          #pragma unroll
          for (int r=0;r<4;r++){
            int b = q*16 + 4*kq + r, j = 32*w + 16*s + l15;
            out[(size_t)b*512 + dir*256 + j] = hval[s][r];
          }
        }
      } else {
        #pragma unroll
        for (int s=0;s<2;s++){
          #pragma unroll
          for (int r=0;r<4;r++){
            int b = 4*kq + r, j = 32*w + 16*s + l15;
            size_t off = ((size_t)dir*64 + q*16 + b)*256 + j;
            hst[off] = hval[s][r];
            cst[off] = c_[s][r];
          }
        }
      }
    } else {
      #pragma unroll
      for (int s=0;s<2;s++){
        #pragma unroll
        for (int r=0;r<4;r++){
          int b = 4*kq + r, j = 32*w + 16*s + l15;
          int L = b + 16*((j>>3)&3);
          *(unsigned short*)(hsl + (j>>5)*1024 + L*16 + (j&7)*2) = f2bf(hval[s][r]);
        }
      }
    }
    __syncthreads();   // h(t+1) visible
  }
}

extern "C" void kernel_launch(void* const* d_in, const int* in_sizes, int n_in,
                              void* d_out, int out_size, void* d_ws, size_t ws_size,
                              hipStream_t stream){
  (void)in_sizes; (void)n_in; (void)out_size;
  const float* x   = (const float*)d_in[0];
  const float* Wf  = (const float*)d_in[1];
  const float* Uf  = (const float*)d_in[2];
  const float* bf_ = (const float*)d_in[3];
  const float* Wb  = (const float*)d_in[4];
  const float* Ub  = (const float*)d_in[5];
  const float* bb  = (const float*)d_in[6];
  float* out = (float*)d_out;
  char* ws = (char*)d_ws;
  unsigned short* wsu = (unsigned short*)ws;
  float* hst = (float*)(ws + OFF_HST);
  float* cst = (float*)(ws + OFF_CST);
  char* xwb = ws + OFF_XW;

  kprep<<<dim3(16,4,4), 256, 0, stream>>>(Wf, Uf, Wb, Ub, wsu);

  long long avail = (long long)ws_size - (long long)OFF_XW;
  int Tseg = (avail > 0) ? (int)(avail / (long long)STEP_BYTES) : 1;
  if (Tseg < 1) Tseg = 1;
  if (Tseg > T_TOTAL) Tseg = T_TOTAL;
  int nseg = (T_TOTAL + Tseg - 1)/Tseg;
  int s0 = 0;
  for (int seg=0; seg<nseg; ++seg){
    int Tthis = (T_TOTAL - s0 < Tseg) ? (T_TOTAL - s0) : Tseg;
    kgemm<<<dim3(Tthis,2), 512, 0, stream>>>(x, bf_, bb, wsu, xwb, s0);
    krec<<<dim3(8), 512, 0, stream>>>(wsu, xwb, hst, cst, out, Tthis,
                                      (seg==0)?1:0, (seg==nseg-1)?1:0);
    s0 += Tthis;
  }
}

// Round 5
// 8307.104 us; speedup vs baseline: 1.3450x; 1.3450x over previous
//
#include <hip/hip_runtime.h>

#define T_TOTAL 2048

typedef short bf16x8 __attribute__((ext_vector_type(8)));
typedef float f32x4 __attribute__((ext_vector_type(4)));

// workspace layout (bytes)
#define OFF_WT  0ull                      // W slots bf16 [2][512 slot][64][16B] (1 MiB)
#define OFF_UT  (1ull<<20)                // U slots bf16 [2][512 slot][64][16B] (1 MiB)
#define OFF_HST (2ull<<20)                // h state f32 [2][64][256]
#define OFF_CST (OFF_HST + (128ull<<10))  // c state f32 [2][64][256]
#define OFF_XW  (3ull<<20)                // xw ring bf16 [Tseg][2][4][1024][16]
#define STEP_BYTES 262144ull              // one step of xw (bf16)

__device__ __forceinline__ unsigned short f2bf(float f){
  unsigned int u = __builtin_bit_cast(unsigned int, f);
  u += 0x7fffu + ((u>>16)&1u);
  return (unsigned short)(u>>16);
}
__device__ __forceinline__ float bfhi2f(unsigned int u){
  unsigned int v = u & 0xffff0000u; return __builtin_bit_cast(float, v);
}
__device__ __forceinline__ float bflo2f(unsigned int u){
  unsigned int v = u << 16; return __builtin_bit_cast(float, v);
}
__device__ __forceinline__ float sigf(float z){ return 1.0f/(1.0f + __expf(-z)); }
__device__ __forceinline__ float tanhf_(float z){ return 2.0f/(1.0f + __expf(-2.0f*z)) - 1.0f; }

// ---------------- prep: all 4 matrices -> fragment-slot layout -------------
// slot layout: [(cg*8+ks)*512 + ((col&15)+16*kq)*8 + e] shorts, cg=col>>4,
// ks=k>>5, kq=(k>>3)&3, e=k&7.
__global__ __launch_bounds__(256) void kprep(const float* __restrict__ Wf, const float* __restrict__ Uf,
                                             const float* __restrict__ Wb, const float* __restrict__ Ub,
                                             unsigned short* __restrict__ ws){
  __shared__ float tile[64][65];
  int mat = blockIdx.z; // 0 Wf, 1 Wb, 2 Uf, 3 Ub
  const float* src = (mat==0)?Wf:(mat==1)?Wb:(mat==2)?Uf:Ub;
  unsigned short* dst = ws + ((mat<2)?0u:524288u) + (unsigned)(mat&1)*262144u;
  int c0 = blockIdx.x*64, k0 = blockIdx.y*64;
  int tx = threadIdx.x & 63, ty = threadIdx.x >> 6;
  #pragma unroll
  for (int j=0;j<16;j++){
    int r = j*4+ty;
    tile[r][tx] = src[(size_t)(k0+r)*1024 + (c0+tx)];
  }
  __syncthreads();
  #pragma unroll
  for (int j=0;j<16;j++){
    int r = j*4+ty;
    int col = c0+r, k = k0+tx;
    int cg = col>>4, ks = k>>5, kq = (k>>3)&3, e = k&7;
    dst[(size_t)(cg*8+ks)*512 + ((col&15)+16*kq)*8 + e] = f2bf(tile[tx][r]);
  }
}

// ---------------- xw GEMM: t-chunked, W resident (regs+LDS) ---------------
// grid (chunks, 2 dir, 4 quad), 512 thr. Each block: 64 timesteps, 16 batches.
__global__ __launch_bounds__(512) void kgemm(const float* __restrict__ x,
        const float* __restrict__ biasF, const float* __restrict__ biasB,
        const unsigned short* __restrict__ wsu, char* __restrict__ xw,
        int s0, int Tthis){
  __shared__ __align__(16) char smem[147456]; // W ks6,7: 128K; A dbuf: 2x8K
  char* abuf = smem + 131072;
  int chunk = blockIdx.x, dir = blockIdx.y, q = blockIdx.z;
  int tid = threadIdx.x, w = tid>>6, l = tid&63;
  int l15 = l&15;
  const char* WT = (const char*)(wsu + (size_t)dir*262144u);
  const float* bias = dir ? biasB : biasF;

  // W residency: wave w owns cols [128w,128w+128) = cg 8w..8w+7.
  bf16x8 wfr[8][6];
  #pragma unroll
  for (int ct=0;ct<8;ct++){
    int cg = 8*w + ct;
    const char* base = WT + (size_t)cg*8192 + (size_t)l*16;
    #pragma unroll
    for (int ks=0;ks<6;ks++) wfr[ct][ks] = *(const bf16x8*)(base + ks*1024);
    #pragma unroll
    for (int k2=0;k2<2;k2++){
      bf16x8 t = *(const bf16x8*)(base + (6+k2)*1024);
      *(bf16x8*)(smem + ((cg*2+k2)*1024 + l*16)) = t;
    }
  }
  float bv[8];
  #pragma unroll
  for (int ct=0;ct<8;ct++) bv[ct] = bias[128*w + ct*16 + l15];

  int b_loc = tid>>5, kk = (tid&31)*8;
  int b = q*16 + b_loc;
  int aslot = (kk>>5)*1024 + (b_loc + 16*((kk>>3)&3))*16;

  // prologue: stage t=0 into abuf[0]
  int nt = Tthis - chunk*64; if (nt > 64) nt = 64; if (nt < 0) nt = 0;
  if (nt > 0){
    int sg = s0 + chunk*64;
    int t_src = dir ? (T_TOTAL-1-sg) : sg;
    const float* px = x + ((size_t)b*T_TOTAL + t_src)*256 + kk;
    float4 v0 = *(const float4*)px;
    float4 v1 = *(const float4*)(px+4);
    uint4 pk;
    pk.x = (unsigned)f2bf(v0.x) | ((unsigned)f2bf(v0.y)<<16);
    pk.y = (unsigned)f2bf(v0.z) | ((unsigned)f2bf(v0.w)<<16);
    pk.z = (unsigned)f2bf(v1.x) | ((unsigned)f2bf(v1.y)<<16);
    pk.w = (unsigned)f2bf(v1.z) | ((unsigned)f2bf(v1.w)<<16);
    *(uint4*)(abuf + aslot) = pk;
  }
  __syncthreads();

  int p = 0;
  for (int tl=0; tl<nt; ++tl){
    // prefetch next t into regs
    float4 v0, v1;
    int have_next = (tl+1 < nt);
    if (have_next){
      int sg = s0 + chunk*64 + tl + 1;
      int t_src = dir ? (T_TOTAL-1-sg) : sg;
      const float* px = x + ((size_t)b*T_TOTAL + t_src)*256 + kk;
      v0 = *(const float4*)px;
      v1 = *(const float4*)(px+4);
    }
    // compute t from abuf[p]
    char* outp = xw + (size_t)(chunk*64+tl)*STEP_BYTES + (size_t)dir*131072u + (size_t)q*32768u;
    #pragma unroll
    for (int half=0; half<2; ++half){
      f32x4 acc[4];
      #pragma unroll
      for (int ci=0;ci<4;ci++){
        float b0 = bv[half*4+ci];
        acc[ci][0]=b0; acc[ci][1]=b0; acc[ci][2]=b0; acc[ci][3]=b0;
      }
      #pragma unroll
      for (int ks=0;ks<8;ks++){
        bf16x8 a = *(const bf16x8*)(abuf + p*8192 + ks*1024 + l*16);
        #pragma unroll
        for (int ci=0;ci<4;ci++){
          int ct = half*4+ci;
          bf16x8 bb;
          if (ks<6) bb = wfr[ct][ks];
          else      bb = *(const bf16x8*)(smem + (((8*w+ct)*2+(ks-6))*1024 + l*16));
          acc[ci] = __builtin_amdgcn_mfma_f32_16x16x32_bf16(a, bb, acc[ci], 0, 0, 0);
        }
      }
      #pragma unroll
      for (int ci=0;ci<4;ci++){
        int ct = half*4+ci;
        int col = 128*w + ct*16 + l15;
        uint2 pk;
        pk.x = (unsigned)f2bf(acc[ci][0]) | ((unsigned)f2bf(acc[ci][1])<<16);
        pk.y = (unsigned)f2bf(acc[ci][2]) | ((unsigned)f2bf(acc[ci][3])<<16);
        *(uint2*)(outp + (size_t)col*32 + (l>>4)*8) = pk;
      }
    }
    // write prefetched t+1 into abuf[p^1]
    if (have_next){
      uint4 pk;
      pk.x = (unsigned)f2bf(v0.x) | ((unsigned)f2bf(v0.y)<<16);
      pk.y = (unsigned)f2bf(v0.z) | ((unsigned)f2bf(v0.w)<<16);
      pk.z = (unsigned)f2bf(v1.x) | ((unsigned)f2bf(v1.y)<<16);
      pk.w = (unsigned)f2bf(v1.z) | ((unsigned)f2bf(v1.w)<<16);
      *(uint4*)(abuf + (p^1)*8192 + aslot) = pk;
    }
    __syncthreads();
    p ^= 1;
  }
}

// ---------------- recurrent scan: 8 blocks = 2 dirs x 4 batch-quads --------
// U on-chip: ks0..5 in 192 regs (VGPR+AGPR unified), ks6,7 in LDS 128K.
// h double-buffered in LDS (2x8K) -> one barrier/step, no hval registers.
__global__ __launch_bounds__(512) void krec(const unsigned short* __restrict__ wsu,
        const char* __restrict__ xw, float* __restrict__ hst, float* __restrict__ cst,
        float* __restrict__ out, int nsteps, int first, int last){
  __shared__ __align__(16) char smem[147456]; // U: 128K; h dbuf: 2x8K
  char* hb = smem + 131072;
  int bid = blockIdx.x;
  int dir = bid>>2, q = bid&3;
  int tid = threadIdx.x, w = tid>>6, l = tid&63;
  int l15 = l&15, kq = l>>4;
  const char* UT = (const char*)(wsu + 524288u + (size_t)dir*262144u);

  bf16x8 ur[2][4][6];
  #pragma unroll
  for (int s=0;s<2;s++){
    #pragma unroll
    for (int g=0;g<4;g++){
      int cg = g*16 + 2*w + s;
      const char* base = UT + (size_t)cg*8192 + (size_t)l*16;
      #pragma unroll
      for (int ks=0;ks<6;ks++) ur[s][g][ks] = *(const bf16x8*)(base + ks*1024);
      #pragma unroll
      for (int k2=0;k2<2;k2++){
        bf16x8 t = *(const bf16x8*)(base + (6+k2)*1024);
        *(bf16x8*)(smem + ((((w*2+s)*4+g)*2+k2)*1024 + l*16)) = t;
      }
    }
  }

  float c_[2][4];
  if (first){
    #pragma unroll
    for (int s=0;s<2;s++){
      #pragma unroll
      for (int r=0;r<4;r++) c_[s][r]=0.0f;
    }
    *(uint4*)(hb + tid*16) = make_uint4(0u,0u,0u,0u);
  } else {
    #pragma unroll
    for (int s=0;s<2;s++){
      #pragma unroll
      for (int r=0;r<4;r++){
        int bb = 4*kq + r, j = 32*w + 16*s + l15;
        size_t off = ((size_t)dir*64 + q*16 + bb)*256 + j;
        float hv = hst[off];
        c_[s][r] = cst[off];
        int L = bb + 16*((j>>3)&3);
        *(unsigned short*)(hb + (j>>5)*1024 + L*16 + (j&7)*2) = f2bf(hv);
      }
    }
  }
  __syncthreads();

  const char* XW = xw + (size_t)dir*131072u + (size_t)q*32768u;
  uint2 xpf[2][4];
  #pragma unroll
  for (int s=0;s<2;s++){
    #pragma unroll
    for (int g=0;g<4;g++){
      int col = g*256 + 32*w + 16*s + l15;
      xpf[s][g] = *(const uint2*)(XW + (size_t)col*32 + kq*8);
    }
  }

  int p = 0;
  for (int t=0; t<nsteps; ++t){
    #pragma unroll
    for (int s=0;s<2;s++){
      f32x4 acc[4];
      #pragma unroll
      for (int g=0;g<4;g++){
        uint2 v = xpf[s][g];
        acc[g][0]=bflo2f(v.x); acc[g][1]=bfhi2f(v.x);
        acc[g][2]=bflo2f(v.y); acc[g][3]=bfhi2f(v.y);
      }
      { // prefetch next step's xw half (consumed next iteration)
        int tn = (t+1 < nsteps) ? (t+1) : t;
        #pragma unroll
        for (int g=0;g<4;g++){
          int col = g*256 + 32*w + 16*s + l15;
          xpf[s][g] = *(const uint2*)(XW + (size_t)tn*STEP_BYTES + (size_t)col*32 + kq*8);
        }
      }
      #pragma unroll
      for (int ks=0;ks<8;ks++){
        bf16x8 a = *(const bf16x8*)(hb + p*8192 + ks*1024 + l*16);
        #pragma unroll
        for (int g=0;g<4;g++){
          bf16x8 bfr;
          if (ks<6) bfr = ur[s][g][ks];
          else      bfr = *(const bf16x8*)(smem + ((((w*2+s)*4+g)*2+(ks-6))*1024 + l*16));
          acc[g] = __builtin_amdgcn_mfma_f32_16x16x32_bf16(a, bfr, acc[g], 0, 0, 0);
        }
      }
      #pragma unroll
      for (int r=0;r<4;r++){
        float ig = sigf(acc[0][r]);
        float fg = sigf(acc[1][r]);
        float gg = tanhf_(acc[2][r]);
        float og = sigf(acc[3][r]);
        float cn = fg*c_[s][r] + ig*gg;
        c_[s][r] = cn;
        float hv = og*tanhf_(cn);
        int bb = 4*kq + r, j = 32*w + 16*s + l15;
        int L = bb + 16*((j>>3)&3);
        *(unsigned short*)(hb + (p^1)*8192 + (j>>5)*1024 + L*16 + (j&7)*2) = f2bf(hv);
        if (t == nsteps-1){
          if (last){
            out[(size_t)(q*16 + bb)*512 + dir*256 + j] = hv;
          } else {
            size_t off = ((size_t)dir*64 + q*16 + bb)*256 + j;
            hst[off] = hv;
            cst[off] = c_[s][r];
          }
        }
      }
    }
    __syncthreads();   // h(t+1) writes visible; xpf regs carry xw(t+1)
    p ^= 1;
  }
}

extern "C" void kernel_launch(void* const* d_in, const int* in_sizes, int n_in,
                              void* d_out, int out_size, void* d_ws, size_t ws_size,
                              hipStream_t stream){
  (void)in_sizes; (void)n_in; (void)out_size;
  const float* x   = (const float*)d_in[0];
  const float* Wf  = (const float*)d_in[1];
  const float* Uf  = (const float*)d_in[2];
  const float* bf_ = (const float*)d_in[3];
  const float* Wb  = (const float*)d_in[4];
  const float* Ub  = (const float*)d_in[5];
  const float* bb  = (const float*)d_in[6];
  float* out = (float*)d_out;
  char* ws = (char*)d_ws;
  unsigned short* wsu = (unsigned short*)ws;
  float* hst = (float*)(ws + OFF_HST);
  float* cst = (float*)(ws + OFF_CST);
  char* xwb = ws + OFF_XW;

  kprep<<<dim3(16,4,4), 256, 0, stream>>>(Wf, Uf, Wb, Ub, wsu);

  long long avail = (long long)ws_size - (long long)OFF_XW;
  int Tseg = (avail > 0) ? (int)(avail / (long long)STEP_BYTES) : 1;
  if (Tseg < 1) Tseg = 1;
  if (Tseg > T_TOTAL) Tseg = T_TOTAL;
  int nseg = (T_TOTAL + Tseg - 1)/Tseg;
  int s0 = 0;
  for (int seg=0; seg<nseg; ++seg){
    int Tthis = (T_TOTAL - s0 < Tseg) ? (T_TOTAL - s0) : Tseg;
    int nchunk = (Tthis + 63)/64;
    kgemm<<<dim3(nchunk,2,4), 512, 0, stream>>>(x, bf_, bb, wsu, xwb, s0, Tthis);
    krec<<<dim3(8), 512, 0, stream>>>(wsu, xwb, hst, cst, out, Tthis,
                                      (seg==0)?1:0, (seg==nseg-1)?1:0);
    s0 += Tthis;
  }
}